// Round 18
// baseline (142.801 us; speedup 1.0000x reference)
//
#include <hip/hip_runtime.h>
#include <hip/hip_bf16.h>

#define CC 64
#define HW 9216
#define IMG 96
#define SPLITS 8
#define SPLEN 1152            // 9216 / 8
#define ITERS 18              // 1152 / 64
#define LOG2E 1.44269504f

typedef _Float16 f16;
typedef __attribute__((ext_vector_type(8))) _Float16 f16x8;
typedef __attribute__((ext_vector_type(4))) _Float16 f16x4;
typedef __attribute__((ext_vector_type(4))) float f32x4;
typedef __attribute__((ext_vector_type(16))) float f32x16;

// ---------------- prepad + transpose: xt[p][ci] (p in 100x100 padded image, 64 f16 rows)
__global__ __launch_bounds__(256) void prepad_kernel(
    const float* __restrict__ x, f16* __restrict__ xt)
{
    __shared__ float tile[64][65];
    const int p0 = blockIdx.x * 64;              // grid 157
    const int t = threadIdx.x;
    const int pl = t & 63;
    const int p = p0 + pl;
    int r = p / 100, c = p % 100;
    bool interior = (r >= 2) && (r < 98) && (c >= 2) && (c < 98);
    int img = (r - 2) * IMG + (c - 2);
    #pragma unroll
    for (int j = 0; j < 16; ++j) {
        int ci = j * 4 + (t >> 6);
        tile[pl][ci] = interior ? x[ci * HW + img] : 0.f;
    }
    __syncthreads();
    const int row16 = t >> 4, chunk = t & 15;
    #pragma unroll
    for (int j = 0; j < 4; ++j) {
        int row = j * 16 + row16;
        int pr = p0 + row;
        if (pr < 10000) {
            f16x4 hv = {(f16)tile[row][chunk * 4 + 0], (f16)tile[row][chunk * 4 + 1],
                        (f16)tile[row][chunk * 4 + 2], (f16)tile[row][chunk * 4 + 3]};
            *(f16x4*)&xt[pr * 64 + chunk * 4] = hv;
        }
    }
}

// ---------------- MFMA conv: dilated 3x3 (9-tap GEMM over ci) + fused 1x1 (center tap)
__global__ __launch_bounds__(256) void conv_mfma_kernel(
    const f16* __restrict__ xt, const float* __restrict__ dW, const float* __restrict__ db,
    const float* __restrict__ cW, const float* __restrict__ cb,
    f16* __restrict__ yq, f16* __restrict__ kt, f16* __restrict__ vt)
{
    __shared__ f16 Wl[9 * 16 * 64];      // [tap][co][ci]
    __shared__ f16 cWl[16 * 64];         // [co][ci]

    const int b = blockIdx.x;            // 144 m-blocks * 4 co-groups
    const int mblk = b >> 2, cog = b & 3;
    const int co0 = cog * 16;
    const int t = threadIdx.x;

    #pragma unroll 4
    for (int j = 0; j < 36; ++j) {       // coalesced read + LDS-scattered write
        int d = j * 256 + t;
        float val = dW[co0 * 576 + d];
        int co  = d / 576;
        int r   = d - co * 576;
        int ci  = r / 9;
        int tap = r - ci * 9;
        Wl[tap * 1024 + co * 64 + ci] = (f16)val;
    }
    #pragma unroll
    for (int j = 0; j < 4; ++j) {
        int d = j * 256 + t;
        cWl[d] = (f16)cW[co0 * CC + d];
    }
    __syncthreads();

    const int w = t >> 6, L = t & 63, g = L >> 4, c16 = L & 15;
    const int ms = mblk * 64 + w * 16;
    const int h = ms / IMG, wc = ms % IMG;
    const int pb = (h + 2) * 100 + (wc + 2) + c16;

    f16x8 Bf[9][2], Bv[2];
    #pragma unroll
    for (int tap = 0; tap < 9; ++tap)
        #pragma unroll
        for (int kc = 0; kc < 2; ++kc)
            Bf[tap][kc] = *(const f16x8*)&Wl[(tap * 16 + c16) * 64 + g * 8 + kc * 32];
    #pragma unroll
    for (int kc = 0; kc < 2; ++kc)
        Bv[kc] = *(const f16x8*)&cWl[c16 * 64 + g * 8 + kc * 32];

    f32x4 accY = (f32x4){0.f, 0.f, 0.f, 0.f};
    f32x4 accV = (f32x4){0.f, 0.f, 0.f, 0.f};

    #pragma unroll
    for (int tap = 0; tap < 9; ++tap) {
        int kh = tap / 3, kw = tap % 3;
        int toff = (2 * kh - 2) * 100 + (2 * kw - 2);
        const f16* ap = xt + (pb + toff) * 64;
        f16x8 A0 = *(const f16x8*)(ap + g * 8);
        f16x8 A1 = *(const f16x8*)(ap + g * 8 + 32);
        accY = __builtin_amdgcn_mfma_f32_16x16x32_f16(A0, Bf[tap][0], accY, 0, 0, 0);
        accY = __builtin_amdgcn_mfma_f32_16x16x32_f16(A1, Bf[tap][1], accY, 0, 0, 0);
        if (tap == 4) {
            accV = __builtin_amdgcn_mfma_f32_16x16x32_f16(A0, Bv[0], accV, 0, 0, 0);
            accV = __builtin_amdgcn_mfma_f32_16x16x32_f16(A1, Bv[1], accV, 0, 0, 0);
        }
    }

    const float dbv = db[co0 + c16], cbv = cb[co0 + c16];
    f16 hy[4];
    #pragma unroll
    for (int j = 0; j < 4; ++j) hy[j] = (f16)(accY[j] + dbv);
    *(f16x4*)&yq[(co0 + c16) * HW + ms + 4 * g] = (f16x4){hy[0], hy[1], hy[2], hy[3]};
    #pragma unroll
    for (int j = 0; j < 4; ++j)
        kt[(ms + 4 * g + j) * 64 + co0 + c16] = hy[j];
    #pragma unroll
    for (int j = 0; j < 4; ++j) {
        int m = ms + 4 * g + j;
        vt[(m & 63) * HW + (co0 + c16) * 144 + (m >> 6)] = (f16)(accV[j] + cbv);
    }
}

// ---------------- MFMA flash attention, 32x32 tiles, wave-split-K:
// block = 64 queries, 4 waves = (query-half qh) x (key-half kh); grid 1152 = 4.5 blk/CU.
// Key-half partials combined in-kernel (split-K rescale) before the acc_ws write.
__global__ __launch_bounds__(256, 4) void attn_kernel(
    const f16* __restrict__ kt, const f16* __restrict__ vt, const f16* __restrict__ yq,
    f16* __restrict__ acc_ws, float* __restrict__ m_ws, float* __restrict__ l_ws)
{
    __shared__ f16 sKT[64 * 72];        // [key_local][ci]
    __shared__ f16 sVT[64 * 72];        // [channel][key_local]
    __shared__ f16 sPS[4 * 32 * 40];    // per-wave P [q(32)][key(32)], stride 40; reused post-loop
    __shared__ float sAL[4 * 32];       // per-wave alpha[query]

    const int t = threadIdx.x;
    const int L = t & 63, w = t >> 6;
    const int l5 = L >> 5, l31 = L & 31;
    const int qh = w & 1, kh = w >> 1;
    const int qb = blockIdx.x >> 3, sp = blockIdx.x & 7;
    const int n0 = qb * 64;
    const int mbase = sp * SPLEN;
    f16* psw = (f16*)sPS + w * 32 * 40;
    float* alw = (float*)sAL + w * 32;

    // Q B-fragments: query = n0 + qh*32 + l31; B[k=kc*16+l5*8+j][n=l31]
    f16x8 qf[4];
    #pragma unroll
    for (int kc = 0; kc < 4; ++kc)
        qf[kc] = *(const f16x8*)(yq + (n0 + qh * 32 + l31) * 64 + kc * 16 + l5 * 8);

    float mi = -1e30f, li = 0.f;
    f32x16 acc[2];
    #pragma unroll
    for (int ct = 0; ct < 2; ++ct)
        #pragma unroll
        for (int r = 0; r < 16; ++r) acc[ct][r] = 0.f;

    for (int it = 0; it < ITERS; ++it) {
        const int m0 = mbase + it * 64;
        __syncthreads();
        #pragma unroll
        for (int rep = 0; rep < 2; ++rep) {
            int idx = t + rep * 256;
            int row = idx >> 3, ch = idx & 7;
            *(uint4*)&sKT[row * 72 + ch * 8] = *(const uint4*)&kt[(m0 + row) * 64 + ch * 8];
            *(uint4*)&sVT[row * 72 + ch * 8] = *(const uint4*)&vt[row * HW + m0 + ch * 8];
        }
        __syncthreads();

        // S^T tile: keys kh*32..+32, queries qh*32..+32; D: col=l31(query), row=key reg-map
        f32x16 st;
        #pragma unroll
        for (int r = 0; r < 16; ++r) st[r] = 0.f;
        #pragma unroll
        for (int kc = 0; kc < 4; ++kc) {
            f16x8 af = *(const f16x8*)&sKT[(kh * 32 + l31) * 72 + kc * 16 + l5 * 8];
            st = __builtin_amdgcn_mfma_f32_32x32x16_f16(af, qf[kc], st, 0, 0, 0);
        }
        // threshold mask to ZERO
        #pragma unroll
        for (int r = 0; r < 16; ++r)
            st[r] = (fabsf(st[r]) > 0.3f) ? st[r] : 0.f;

        // row max: 15 local + 1 shfl
        float q4[4];
        #pragma unroll
        for (int rq = 0; rq < 4; ++rq)
            q4[rq] = fmaxf(fmaxf(st[rq * 4 + 0], st[rq * 4 + 1]),
                           fmaxf(st[rq * 4 + 2], st[rq * 4 + 3]));
        float mx = fmaxf(fmaxf(q4[0], q4[1]), fmaxf(q4[2], q4[3]));
        mx = fmaxf(mx, __shfl_xor(mx, 32, 64));
        float mnew = fmaxf(mi, mx);
        float nL = mnew * LOG2E;
        float alpha = __builtin_amdgcn_exp2f(mi * LOG2E - nL);
        mi = mnew;

        // p = exp2(s*L2E - nL); packed b64 P-writes; partial li
        float ls = 0.f;
        #pragma unroll
        for (int rq = 0; rq < 4; ++rq) {
            float p0 = __builtin_amdgcn_exp2f(fmaf(st[rq * 4 + 0], LOG2E, -nL));
            float p1 = __builtin_amdgcn_exp2f(fmaf(st[rq * 4 + 1], LOG2E, -nL));
            float p2 = __builtin_amdgcn_exp2f(fmaf(st[rq * 4 + 2], LOG2E, -nL));
            float p3 = __builtin_amdgcn_exp2f(fmaf(st[rq * 4 + 3], LOG2E, -nL));
            ls += (p0 + p1) + (p2 + p3);
            unsigned u0 = __builtin_bit_cast(unsigned int, __builtin_amdgcn_cvt_pkrtz(p0, p1));
            unsigned u1 = __builtin_bit_cast(unsigned int, __builtin_amdgcn_cvt_pkrtz(p2, p3));
            uint2 uv; uv.x = u0; uv.y = u1;
            *(uint2*)&psw[l31 * 40 + rq * 8 + l5 * 4] = uv;
        }
        li = li * alpha + ls;

        // alpha redistribution (acc rows are reg-mapped queries)
        if (l5 == 0) alw[l31] = alpha;
        f32x4 aj[4];
        #pragma unroll
        for (int rq = 0; rq < 4; ++rq)
            aj[rq] = *(const f32x4*)&alw[rq * 8 + l5 * 4];
        #pragma unroll
        for (int ct = 0; ct < 2; ++ct)
            #pragma unroll
            for (int r = 0; r < 16; ++r)
                acc[ct][r] *= aj[r >> 2][r & 3];

        // PV over this wave's 32 keys: A = P, B = V^T (keys kh*32 + kc2*16 + l5*8)
        f16x8 pa[2];
        #pragma unroll
        for (int kc2 = 0; kc2 < 2; ++kc2)
            pa[kc2] = *(const f16x8*)&psw[l31 * 40 + kc2 * 16 + l5 * 8];
        #pragma unroll
        for (int ct = 0; ct < 2; ++ct)
            #pragma unroll
            for (int kc2 = 0; kc2 < 2; ++kc2) {
                f16x8 vb = *(const f16x8*)&sVT[(ct * 32 + l31) * 72 + kh * 32 + kc2 * 16 + l5 * 8];
                acc[ct] = __builtin_amdgcn_mfma_f32_32x32x16_f16(pa[kc2], vb, acc[ct], 0, 0, 0);
            }
    }

    // per-query row-sum (combine l5 halves)
    float li_tot = li + __shfl_xor(li, 32, 64);

    // ---- split-K combine of the two key-half waves (reuse sPS memory) ----
    __syncthreads();
    f16* accx  = (f16*)sPS;                          // [qh][64 lanes][32] stride 34
    float* mix = (float*)((char*)sPS + 8704);        // [2][32]
    float* lix = mix + 64;                           // [2][32]
    if (kh == 1) {
        f16* dst = accx + (qh * 64 + L) * 34;
        #pragma unroll
        for (int ct = 0; ct < 2; ++ct)
            #pragma unroll
            for (int rq = 0; rq < 4; ++rq) {
                unsigned u0 = __builtin_bit_cast(unsigned int,
                    __builtin_amdgcn_cvt_pkrtz(acc[ct][rq * 4 + 0], acc[ct][rq * 4 + 1]));
                unsigned u1 = __builtin_bit_cast(unsigned int,
                    __builtin_amdgcn_cvt_pkrtz(acc[ct][rq * 4 + 2], acc[ct][rq * 4 + 3]));
                uint2 uv; uv.x = u0; uv.y = u1;
                *(uint2*)(dst + ct * 16 + rq * 4) = uv;
            }
        if (l5 == 0) {
            mix[qh * 32 + l31] = mi;
            lix[qh * 32 + l31] = li_tot;
        }
    }
    __syncthreads();
    if (kh == 0) {
        float mi2 = mix[qh * 32 + l31], li2 = lix[qh * 32 + l31];
        float mnew = fmaxf(mi, mi2);
        float e1 = __builtin_amdgcn_exp2f((mi  - mnew) * LOG2E);
        float e2 = __builtin_amdgcn_exp2f((mi2 - mnew) * LOG2E);
        float lsum = li_tot * e1 + li2 * e2;
        if (l5 == 0) {
            alw[l31] = e1;
            sAL[(w + 2) * 32 + l31] = e2;    // waves 2/3's alw slots are free now
        }
        f32x4 a1[4], a2[4];
        #pragma unroll
        for (int rq = 0; rq < 4; ++rq) {
            a1[rq] = *(const f32x4*)&alw[rq * 8 + l5 * 4];
            a2[rq] = *(const f32x4*)&sAL[(w + 2) * 32 + rq * 8 + l5 * 4];
        }
        const f16* src = accx + (qh * 64 + L) * 34;
        const int base = blockIdx.x;
        #pragma unroll
        for (int ct = 0; ct < 2; ++ct) {
            f16 pr[16];
            *(f16x8*)&pr[0] = *(const f16x8*)(src + ct * 16);
            *(f16x8*)&pr[8] = *(const f16x8*)(src + ct * 16 + 8);
            #pragma unroll
            for (int r = 0; r < 16; ++r) {
                float cv = acc[ct][r] * a1[r >> 2][r & 3] + (float)pr[r] * a2[r >> 2][r & 3];
                int ql = qh * 32 + (r & 3) + 8 * (r >> 2) + 4 * l5;
                acc_ws[base * 4096 + ql * 64 + ct * 32 + l31] = (f16)cv;
            }
        }
        if (l5 == 0) {
            m_ws[base * 64 + qh * 32 + l31] = mnew;
            l_ws[base * 64 + qh * 32 + l31] = lsum;
        }
    }
}

// ---------------- merge splits + residual + transpose; grid 576 (16-row tiles, 64-q blocks)
__global__ __launch_bounds__(256) void merge_kernel(
    const f16* __restrict__ acc_ws, const float* __restrict__ m_ws, const float* __restrict__ l_ws,
    const float* __restrict__ x, float* __restrict__ out)
{
    __shared__ float wsh[SPLITS * 16];
    __shared__ float att[64 * 17];
    const int qb = blockIdx.x >> 2, sub = blockIdx.x & 3;
    const int r0 = sub * 16;
    const int t = threadIdx.x;
    if (t < 16) {
        int row = r0 + t;
        float ms = -1e30f;
        float mv[SPLITS];
        #pragma unroll
        for (int sp = 0; sp < SPLITS; ++sp) {
            mv[sp] = m_ws[(qb * SPLITS + sp) * 64 + row];
            ms = fmaxf(ms, mv[sp]);
        }
        float Lsum = 0.f, ev[SPLITS];
        #pragma unroll
        for (int sp = 0; sp < SPLITS; ++sp) {
            ev[sp] = __builtin_amdgcn_exp2f((mv[sp] - ms) * LOG2E);
            Lsum += l_ws[(qb * SPLITS + sp) * 64 + row] * ev[sp];
        }
        float inv = 1.f / Lsum;
        #pragma unroll
        for (int sp = 0; sp < SPLITS; ++sp)
            wsh[sp * 16 + t] = ev[sp] * inv;
    }
    __syncthreads();
    for (int i = t; i < 1024; i += 256) {
        int rr = i >> 6, c = i & 63;
        float v = 0.f;
        #pragma unroll
        for (int sp = 0; sp < SPLITS; ++sp)
            v += (float)acc_ws[(qb * SPLITS + sp) * 4096 + (r0 + rr) * 64 + c] * wsh[sp * 16 + rr];
        att[c * 17 + rr] = v;
    }
    __syncthreads();
    const int n0 = qb * 64 + r0;
    for (int i = t; i < 1024; i += 256) {
        int c = i >> 4, r = i & 15;
        int idx = c * HW + n0 + r;
        out[idx] = x[idx] + att[c * 17 + r];
    }
}

extern "C" void kernel_launch(void* const* d_in, const int* in_sizes, int n_in,
                              void* d_out, int out_size, void* d_ws, size_t ws_size,
                              hipStream_t stream)
{
    const float* x  = (const float*)d_in[0];
    const float* dW = (const float*)d_in[1];
    const float* db = (const float*)d_in[2];
    const float* cW = (const float*)d_in[3];
    const float* cb = (const float*)d_in[4];
    float* out = (float*)d_out;

    char* ws = (char*)d_ws;
    f16* kt     = (f16*)(ws);                        // 1,179,648 B
    f16* yq     = (f16*)(ws + 1179648);              // 1,179,648 B
    f16* vt     = (f16*)(ws + 2359296);              // 1,179,648 B
    f16* xt     = (f16*)(ws + 3538944);              // 1,280,000 B
    f16* acc_ws = (f16*)(ws + 4818944);              // 9,437,184 B (1152 blk * 4096)
    float* m_ws = (float*)(ws + 14256128);           //   294,912 B
    float* l_ws = (float*)(ws + 14551040);           //   294,912 B
                                                     // total 14,845,952 B

    prepad_kernel<<<dim3(157), dim3(256), 0, stream>>>(x, xt);
    conv_mfma_kernel<<<dim3(576), dim3(256), 0, stream>>>(xt, dW, db, cW, cb, yq, kt, vt);
    attn_kernel<<<dim3(144 * SPLITS), dim3(256), 0, stream>>>(kt, vt, yq, acc_ws, m_ws, l_ws);
    merge_kernel<<<dim3(576), dim3(256), 0, stream>>>(acc_ws, m_ws, l_ws, x, out);
}

// Round 19
// 137.879 us; speedup vs baseline: 1.0357x; 1.0357x over previous
//
#include <hip/hip_runtime.h>
#include <hip/hip_bf16.h>

#define CC 64
#define HW 9216
#define IMG 96
#define SPLITS 8
#define SPLEN 1152            // 9216 / 8
#define ITERS 18              // 1152 / 64
#define LOG2E 1.44269504f

typedef _Float16 f16;
typedef __attribute__((ext_vector_type(8))) _Float16 f16x8;
typedef __attribute__((ext_vector_type(4))) _Float16 f16x4;
typedef __attribute__((ext_vector_type(4))) float f32x4;
typedef __attribute__((ext_vector_type(16))) float f32x16;

// ---------------- prepad + transpose: xt[p][ci] (p in 100x100 padded image, 64 f16 rows)
__global__ __launch_bounds__(256) void prepad_kernel(
    const float* __restrict__ x, f16* __restrict__ xt)
{
    __shared__ float tile[64][65];
    const int p0 = blockIdx.x * 64;              // grid 157
    const int t = threadIdx.x;
    const int pl = t & 63;
    const int p = p0 + pl;
    int r = p / 100, c = p % 100;
    bool interior = (r >= 2) && (r < 98) && (c >= 2) && (c < 98);
    int img = (r - 2) * IMG + (c - 2);
    #pragma unroll
    for (int j = 0; j < 16; ++j) {
        int ci = j * 4 + (t >> 6);
        tile[pl][ci] = interior ? x[ci * HW + img] : 0.f;
    }
    __syncthreads();
    const int row16 = t >> 4, chunk = t & 15;
    #pragma unroll
    for (int j = 0; j < 4; ++j) {
        int row = j * 16 + row16;
        int pr = p0 + row;
        if (pr < 10000) {
            f16x4 hv = {(f16)tile[row][chunk * 4 + 0], (f16)tile[row][chunk * 4 + 1],
                        (f16)tile[row][chunk * 4 + 2], (f16)tile[row][chunk * 4 + 3]};
            *(f16x4*)&xt[pr * 64 + chunk * 4] = hv;
        }
    }
}

// ---------------- MFMA conv: dilated 3x3 (9-tap GEMM over ci) + fused 1x1 (center tap)
__global__ __launch_bounds__(256) void conv_mfma_kernel(
    const f16* __restrict__ xt, const float* __restrict__ dW, const float* __restrict__ db,
    const float* __restrict__ cW, const float* __restrict__ cb,
    f16* __restrict__ yq, f16* __restrict__ kt, f16* __restrict__ vt)
{
    __shared__ f16 Wl[9 * 16 * 64];      // [tap][co][ci]
    __shared__ f16 cWl[16 * 64];         // [co][ci]

    const int b = blockIdx.x;            // 144 m-blocks * 4 co-groups
    const int mblk = b >> 2, cog = b & 3;
    const int co0 = cog * 16;
    const int t = threadIdx.x;

    #pragma unroll 4
    for (int j = 0; j < 36; ++j) {       // coalesced read + LDS-scattered write
        int d = j * 256 + t;
        float val = dW[co0 * 576 + d];
        int co  = d / 576;
        int r   = d - co * 576;
        int ci  = r / 9;
        int tap = r - ci * 9;
        Wl[tap * 1024 + co * 64 + ci] = (f16)val;
    }
    #pragma unroll
    for (int j = 0; j < 4; ++j) {
        int d = j * 256 + t;
        cWl[d] = (f16)cW[co0 * CC + d];
    }
    __syncthreads();

    const int w = t >> 6, L = t & 63, g = L >> 4, c16 = L & 15;
    const int ms = mblk * 64 + w * 16;
    const int h = ms / IMG, wc = ms % IMG;
    const int pb = (h + 2) * 100 + (wc + 2) + c16;

    f16x8 Bf[9][2], Bv[2];
    #pragma unroll
    for (int tap = 0; tap < 9; ++tap)
        #pragma unroll
        for (int kc = 0; kc < 2; ++kc)
            Bf[tap][kc] = *(const f16x8*)&Wl[(tap * 16 + c16) * 64 + g * 8 + kc * 32];
    #pragma unroll
    for (int kc = 0; kc < 2; ++kc)
        Bv[kc] = *(const f16x8*)&cWl[c16 * 64 + g * 8 + kc * 32];

    f32x4 accY = (f32x4){0.f, 0.f, 0.f, 0.f};
    f32x4 accV = (f32x4){0.f, 0.f, 0.f, 0.f};

    #pragma unroll
    for (int tap = 0; tap < 9; ++tap) {
        int kh = tap / 3, kw = tap % 3;
        int toff = (2 * kh - 2) * 100 + (2 * kw - 2);
        const f16* ap = xt + (pb + toff) * 64;
        f16x8 A0 = *(const f16x8*)(ap + g * 8);
        f16x8 A1 = *(const f16x8*)(ap + g * 8 + 32);
        accY = __builtin_amdgcn_mfma_f32_16x16x32_f16(A0, Bf[tap][0], accY, 0, 0, 0);
        accY = __builtin_amdgcn_mfma_f32_16x16x32_f16(A1, Bf[tap][1], accY, 0, 0, 0);
        if (tap == 4) {
            accV = __builtin_amdgcn_mfma_f32_16x16x32_f16(A0, Bv[0], accV, 0, 0, 0);
            accV = __builtin_amdgcn_mfma_f32_16x16x32_f16(A1, Bv[1], accV, 0, 0, 0);
        }
    }

    const float dbv = db[co0 + c16], cbv = cb[co0 + c16];
    f16 hy[4];
    #pragma unroll
    for (int j = 0; j < 4; ++j) hy[j] = (f16)(accY[j] + dbv);
    *(f16x4*)&yq[(co0 + c16) * HW + ms + 4 * g] = (f16x4){hy[0], hy[1], hy[2], hy[3]};
    #pragma unroll
    for (int j = 0; j < 4; ++j)
        kt[(ms + 4 * g + j) * 64 + co0 + c16] = hy[j];
    #pragma unroll
    for (int j = 0; j < 4; ++j) {
        int m = ms + 4 * g + j;
        vt[(m & 63) * HW + (co0 + c16) * 144 + (m >> 6)] = (f16)(accV[j] + cbv);
    }
}

// ---------------- MFMA flash attention, 32x32x16 tiles (R16/R17 structure)
// + wave-uniform skip-alpha fast path: rescale work only when the running max increases.
__global__ __launch_bounds__(256, 3) void attn_kernel(
    const f16* __restrict__ kt, const f16* __restrict__ vt, const f16* __restrict__ yq,
    f16* __restrict__ acc_ws, float* __restrict__ m_ws, float* __restrict__ l_ws)
{
    __shared__ f16 sKT[64 * 72];        // [key_local][ci], stride 144 B
    __shared__ f16 sVT[64 * 72];        // [channel][key_local]
    __shared__ f16 sPS[4 * 32 * 72];    // per-wave P [query_local(32)][key(64)]
    __shared__ float sAL[4 * 32];       // per-wave alpha[query]

    const int t = threadIdx.x;
    const int L = t & 63, w = t >> 6;
    const int l5 = L >> 5, l31 = L & 31;
    const int qb = blockIdx.x >> 3, sp = blockIdx.x & 7;
    const int n0 = qb * 128;
    const int mbase = sp * SPLEN;
    f16* psw = (f16*)sPS + w * 32 * 72;
    float* alw = (float*)sAL + w * 32;

    // Q B-fragments (query = n0 + 32w + l31, ci chunks of 16)
    f16x8 qf[4];
    #pragma unroll
    for (int kc = 0; kc < 4; ++kc)
        qf[kc] = *(const f16x8*)(yq + (n0 + w * 32 + l31) * 64 + kc * 16 + l5 * 8);

    float mi = -1e30f, li = 0.f;        // per-lane query state (li = partial over l5 half)
    f32x16 acc[2];
    #pragma unroll
    for (int ct = 0; ct < 2; ++ct)
        #pragma unroll
        for (int r = 0; r < 16; ++r) acc[ct][r] = 0.f;

    for (int it = 0; it < ITERS; ++it) {
        const int m0 = mbase + it * 64;
        __syncthreads();
        #pragma unroll
        for (int rep = 0; rep < 2; ++rep) {
            int idx = t + rep * 256;
            int row = idx >> 3, ch = idx & 7;
            *(uint4*)&sKT[row * 72 + ch * 8] = *(const uint4*)&kt[(m0 + row) * 64 + ch * 8];
            *(uint4*)&sVT[row * 72 + ch * 8] = *(const uint4*)&vt[row * HW + m0 + ch * 8];
        }
        __syncthreads();

        // S^T: D[key32-tile][query]; lane: query=l31, keys kt2*32 + 8*(r>>2) + 4*l5 + (r&3)
        f32x16 st[2];
        #pragma unroll
        for (int kt2 = 0; kt2 < 2; ++kt2) {
            f32x16 d;
            #pragma unroll
            for (int r = 0; r < 16; ++r) d[r] = 0.f;
            #pragma unroll
            for (int kc = 0; kc < 4; ++kc) {
                f16x8 af = *(const f16x8*)&sKT[(kt2 * 32 + l31) * 72 + kc * 16 + l5 * 8];
                d = __builtin_amdgcn_mfma_f32_32x32x16_f16(af, qf[kc], d, 0, 0, 0);
            }
            st[kt2] = d;
        }
        // threshold mask to ZERO
        #pragma unroll
        for (int kt2 = 0; kt2 < 2; ++kt2)
            #pragma unroll
            for (int r = 0; r < 16; ++r)
                st[kt2][r] = (fabsf(st[kt2][r]) > 0.3f) ? st[kt2][r] : 0.f;

        // row max: 31 local + 1 shfl (partner l5 holds other half of this query's keys)
        float q8[8];
        #pragma unroll
        for (int kt2 = 0; kt2 < 2; ++kt2)
            #pragma unroll
            for (int rq = 0; rq < 4; ++rq)
                q8[kt2 * 4 + rq] = fmaxf(fmaxf(st[kt2][rq * 4 + 0], st[kt2][rq * 4 + 1]),
                                         fmaxf(st[kt2][rq * 4 + 2], st[kt2][rq * 4 + 3]));
        float mx = fmaxf(fmaxf(fmaxf(q8[0], q8[1]), fmaxf(q8[2], q8[3])),
                         fmaxf(fmaxf(q8[4], q8[5]), fmaxf(q8[6], q8[7])));
        mx = fmaxf(mx, __shfl_xor(mx, 32, 64));
        float mnew = fmaxf(mi, mx);
        unsigned long long inc = __ballot(mnew > mi);   // wave-uniform
        float nL = mnew * LOG2E;

        // p = exp2(s*L2E - nL); immediate packed b64 P-writes; partial sum ls
        float ls = 0.f;
        #pragma unroll
        for (int kt2 = 0; kt2 < 2; ++kt2)
            #pragma unroll
            for (int rq = 0; rq < 4; ++rq) {
                float p0 = __builtin_amdgcn_exp2f(fmaf(st[kt2][rq * 4 + 0], LOG2E, -nL));
                float p1 = __builtin_amdgcn_exp2f(fmaf(st[kt2][rq * 4 + 1], LOG2E, -nL));
                float p2 = __builtin_amdgcn_exp2f(fmaf(st[kt2][rq * 4 + 2], LOG2E, -nL));
                float p3 = __builtin_amdgcn_exp2f(fmaf(st[kt2][rq * 4 + 3], LOG2E, -nL));
                ls += (p0 + p1) + (p2 + p3);
                unsigned u0 = __builtin_bit_cast(unsigned int, __builtin_amdgcn_cvt_pkrtz(p0, p1));
                unsigned u1 = __builtin_bit_cast(unsigned int, __builtin_amdgcn_cvt_pkrtz(p2, p3));
                uint2 uv; uv.x = u0; uv.y = u1;
                *(uint2*)&psw[l31 * 72 + kt2 * 32 + rq * 8 + l5 * 4] = uv;
            }

        if (inc) {
            // slow path: some query's max increased -> rescale acc and li
            float alpha = __builtin_amdgcn_exp2f(mi * LOG2E - nL);
            li = li * alpha + ls;
            if (l5 == 0) alw[l31] = alpha;
            f32x4 aj[4];
            #pragma unroll
            for (int rq = 0; rq < 4; ++rq)
                aj[rq] = *(const f32x4*)&alw[rq * 8 + l5 * 4];
            #pragma unroll
            for (int ct = 0; ct < 2; ++ct)
                #pragma unroll
                for (int r = 0; r < 16; ++r)
                    acc[ct][r] *= aj[r >> 2][r & 3];
        } else {
            li += ls;                    // alpha == 1 for every lane
        }
        mi = mnew;

        // PV: A = P (4 k-chunks, reused over 2 c-tiles), B = V^T
        f16x8 pa[4];
        #pragma unroll
        for (int kc = 0; kc < 4; ++kc)
            pa[kc] = *(const f16x8*)&psw[l31 * 72 + kc * 16 + l5 * 8];
        #pragma unroll
        for (int ct = 0; ct < 2; ++ct)
            #pragma unroll
            for (int kc = 0; kc < 4; ++kc) {
                f16x8 vb = *(const f16x8*)&sVT[(ct * 32 + l31) * 72 + kc * 16 + l5 * 8];
                acc[ct] = __builtin_amdgcn_mfma_f32_32x32x16_f16(pa[kc], vb, acc[ct], 0, 0, 0);
            }
    }

    // finish row-sum (partner halves)
    float li_tot = li + __shfl_xor(li, 32, 64);

    // write partials: acc_ws[base*8192 + q_local*64 + c]
    const int base = blockIdx.x;
    #pragma unroll
    for (int ct = 0; ct < 2; ++ct)
        #pragma unroll
        for (int r = 0; r < 16; ++r) {
            int ql = w * 32 + (r & 3) + 8 * (r >> 2) + 4 * l5;
            int c  = ct * 32 + l31;
            acc_ws[base * 8192 + ql * 64 + c] = (f16)acc[ct][r];
        }
    if (l5 == 0) {
        m_ws[base * 128 + w * 32 + l31] = mi;    // unscaled units
        l_ws[base * 128 + w * 32 + l31] = li_tot;
    }
}

// ---------------- merge splits + residual + transpose; grid 576 (16-row tiles, 128-q blocks)
__global__ __launch_bounds__(256) void merge_kernel(
    const f16* __restrict__ acc_ws, const float* __restrict__ m_ws, const float* __restrict__ l_ws,
    const float* __restrict__ x, float* __restrict__ out)
{
    __shared__ float wsh[SPLITS * 16];
    __shared__ float att[64 * 17];
    const int b = blockIdx.x;            // 576 tiles of 16 query rows
    const int row0 = b * 16;
    const int qb = row0 >> 7;            // 16-row tile never crosses a 128-q block
    const int ql0 = row0 & 127;
    const int t = threadIdx.x;
    if (t < 16) {
        int ql = ql0 + t;
        float ms = -1e30f;
        float mv[SPLITS];
        #pragma unroll
        for (int sp = 0; sp < SPLITS; ++sp) {
            mv[sp] = m_ws[(qb * SPLITS + sp) * 128 + ql];
            ms = fmaxf(ms, mv[sp]);
        }
        float Lsum = 0.f, ev[SPLITS];
        #pragma unroll
        for (int sp = 0; sp < SPLITS; ++sp) {
            ev[sp] = __builtin_amdgcn_exp2f((mv[sp] - ms) * LOG2E);
            Lsum += l_ws[(qb * SPLITS + sp) * 128 + ql] * ev[sp];
        }
        float inv = 1.f / Lsum;
        #pragma unroll
        for (int sp = 0; sp < SPLITS; ++sp)
            wsh[sp * 16 + t] = ev[sp] * inv;
    }
    __syncthreads();
    for (int i = t; i < 1024; i += 256) {
        int rr = i >> 6, c = i & 63;         // c fast -> coalesced acc_ws reads
        float v = 0.f;
        #pragma unroll
        for (int sp = 0; sp < SPLITS; ++sp)
            v += (float)acc_ws[(qb * SPLITS + sp) * 8192 + (ql0 + rr) * 64 + c] * wsh[sp * 16 + rr];
        att[c * 17 + rr] = v;
    }
    __syncthreads();
    for (int i = t; i < 1024; i += 256) {
        int c = i >> 4, r = i & 15;
        int idx = c * HW + row0 + r;
        out[idx] = x[idx] + att[c * 17 + r];
    }
}

extern "C" void kernel_launch(void* const* d_in, const int* in_sizes, int n_in,
                              void* d_out, int out_size, void* d_ws, size_t ws_size,
                              hipStream_t stream)
{
    const float* x  = (const float*)d_in[0];
    const float* dW = (const float*)d_in[1];
    const float* db = (const float*)d_in[2];
    const float* cW = (const float*)d_in[3];
    const float* cb = (const float*)d_in[4];
    float* out = (float*)d_out;

    char* ws = (char*)d_ws;
    f16* kt     = (f16*)(ws);                        // 1,179,648 B
    f16* yq     = (f16*)(ws + 1179648);              // 1,179,648 B
    f16* vt     = (f16*)(ws + 2359296);              // 1,179,648 B
    f16* xt     = (f16*)(ws + 3538944);              // 1,280,000 B (xt[p][ci])
    f16* acc_ws = (f16*)(ws + 4818944);              // 9,437,184 B (576 blk * 8192)
    float* m_ws = (float*)(ws + 14256128);           //   294,912 B (576 * 128)
    float* l_ws = (float*)(ws + 14551040);           //   294,912 B
                                                     // total 14,845,952 B

    prepad_kernel<<<dim3(157), dim3(256), 0, stream>>>(x, xt);
    conv_mfma_kernel<<<dim3(576), dim3(256), 0, stream>>>(xt, dW, db, cW, cb, yq, kt, vt);
    attn_kernel<<<dim3(72 * SPLITS), dim3(256), 0, stream>>>(kt, vt, yq, acc_ws, m_ws, l_ws);
    merge_kernel<<<dim3(576), dim3(256), 0, stream>>>(acc_ws, m_ws, l_ws, x, out);
}